// Round 2
// baseline (982.037 us; speedup 1.0000x reference)
//
#include <hip/hip_runtime.h>
#include <hip/hip_bf16.h>
#include <math.h>

#define N_NODES 100000
#define F_IN 512
#define H_DIM 16
#define C_DIM 40

// ---------------- CSR build: histogram / dinv / scan / reorder ----------------

__global__ void hist_kernel(const int* __restrict__ dst, int* __restrict__ cnt, int E) {
    int e = blockIdx.x * blockDim.x + threadIdx.x;
    if (e < E) atomicAdd(&cnt[dst[e]], 1);
}

__global__ void dinv_kernel(const int* __restrict__ cnt, float* __restrict__ dinv, int N) {
    int i = blockIdx.x * blockDim.x + threadIdx.x;
    if (i < N) dinv[i] = rsqrtf((float)(cnt[i] + 1));  // +1 = self-loop
}

// per-block exclusive scan (in place over cnt->S), block totals to BS
__global__ void __launch_bounds__(256) scan1_kernel(int* __restrict__ S, int* __restrict__ BS, int N) {
    __shared__ int buf[2][256];
    int tid = threadIdx.x;
    int gi = blockIdx.x * 256 + tid;
    int v = (gi < N) ? S[gi] : 0;
    int cur = 0;
    buf[0][tid] = v;
    __syncthreads();
    for (int off = 1; off < 256; off <<= 1) {
        int t = buf[cur][tid] + ((tid >= off) ? buf[cur][tid - off] : 0);
        cur ^= 1;
        buf[cur][tid] = t;
        __syncthreads();
    }
    int inc = buf[cur][tid];
    if (gi < N) S[gi] = inc - v;               // exclusive
    if (tid == 255) BS[blockIdx.x] = inc;      // block total
}

// single-block exclusive scan of block sums (NB <= 512)
__global__ void __launch_bounds__(512) scan2_kernel(int* __restrict__ BS, int NB) {
    __shared__ int buf[2][512];
    int tid = threadIdx.x;
    int v = (tid < NB) ? BS[tid] : 0;
    int cur = 0;
    buf[0][tid] = v;
    __syncthreads();
    for (int off = 1; off < 512; off <<= 1) {
        int t = buf[cur][tid] + ((tid >= off) ? buf[cur][tid - off] : 0);
        cur ^= 1;
        buf[cur][tid] = t;
        __syncthreads();
    }
    if (tid < NB) BS[tid] = buf[cur][tid] - v;  // exclusive
}

__global__ void scan3_kernel(int* __restrict__ S, const int* __restrict__ BS, int N) {
    int i = blockIdx.x * blockDim.x + threadIdx.x;
    if (i < N) S[i] += BS[i >> 8];
}

// bump-reorder: after this, S[n] == end of bucket n (orig start[n+1])
__global__ void reorder_kernel(const int* __restrict__ src, const int* __restrict__ dst,
                               int* __restrict__ S, int* __restrict__ eidx, int E) {
    int e = blockIdx.x * blockDim.x + threadIdx.x;
    if (e < E) {
        int p = atomicAdd(&S[dst[e]], 1);
        eidx[p] = src[e];
    }
}

// ---------------- GEMM1: g1 = (x @ W1) * dinv  (4 rows per thread) ----------------

__global__ void __launch_bounds__(256) gemm1_kernel(const float* __restrict__ x,
                                                    const float* __restrict__ W1,
                                                    const float* __restrict__ dinv,
                                                    float* __restrict__ g1, int N) {
    __shared__ float w[F_IN * H_DIM];  // 32 KB
    {
        float4* w4 = (float4*)w;
        const float4* W4 = (const float4*)W1;
        for (int i = threadIdx.x; i < F_IN * H_DIM / 4; i += 256) w4[i] = W4[i];
    }
    __syncthreads();
    int r0 = blockIdx.x * 1024 + threadIdx.x;
    float acc[4][H_DIM];
#pragma unroll
    for (int j = 0; j < 4; j++)
#pragma unroll
        for (int k = 0; k < H_DIM; k++) acc[j][k] = 0.0f;
    const float4* xr[4];
#pragma unroll
    for (int j = 0; j < 4; j++) {
        int row = r0 + 256 * j;
        int cr = row < N ? row : 0;
        xr[j] = (const float4*)(x + (size_t)cr * F_IN);
    }
    const float4* w4 = (const float4*)w;
    for (int f4 = 0; f4 < F_IN / 4; ++f4) {
        float xv[4][4];
#pragma unroll
        for (int j = 0; j < 4; j++) *(float4*)xv[j] = xr[j][f4];
#pragma unroll
        for (int q = 0; q < 4; q++) {
            float wq[H_DIM];
#pragma unroll
            for (int p = 0; p < 4; p++) *(float4*)&wq[4 * p] = w4[(f4 * 4 + q) * 4 + p];
#pragma unroll
            for (int j = 0; j < 4; j++) {
                float s = xv[j][q];
#pragma unroll
                for (int k = 0; k < H_DIM; k++) acc[j][k] += s * wq[k];
            }
        }
    }
#pragma unroll
    for (int j = 0; j < 4; j++) {
        int row = r0 + 256 * j;
        if (row < N) {
            float di = dinv[row];
            float4* o = (float4*)(g1 + (size_t)row * H_DIM);
#pragma unroll
            for (int p = 0; p < 4; p++)
                o[p] = make_float4(acc[j][4 * p] * di, acc[j][4 * p + 1] * di,
                                   acc[j][4 * p + 2] * di, acc[j][4 * p + 3] * di);
        }
    }
}

// ---------------- aggregation (gather-sum over CSR), layer-specific epilogues ----------------

// layer 1: g2 = dinv * relu(dinv*(sum_src g1 + g1_self) + b1)
__global__ void __launch_bounds__(256) agg1_kernel(const int* __restrict__ S, const int* __restrict__ eidx,
                                                   const float* __restrict__ g1, const float* __restrict__ dinv,
                                                   const float* __restrict__ b1, float* __restrict__ g2, int N) {
    int t = blockIdx.x * 256 + threadIdx.x;
    int n = t >> 4;
    if (n >= N) return;
    int k = t & 15;
    int lo = (n == 0) ? 0 : S[n - 1];
    int hi = S[n];
    float sum = g1[t];  // self-loop
    for (int e = lo; e < hi; ++e) {
        int s = eidx[e];
        sum += g1[s * H_DIM + k];
    }
    float di = dinv[n];
    float hb = fmaxf(di * sum + b1[k], 0.0f);
    g2[t] = di * hb;
}

// layer 2: s2 = sum_src g2 + g2_self (dinv applied in final)
__global__ void __launch_bounds__(256) agg2_kernel(const int* __restrict__ S, const int* __restrict__ eidx,
                                                   const float* __restrict__ g2, float* __restrict__ s2, int N) {
    int t = blockIdx.x * 256 + threadIdx.x;
    int n = t >> 4;
    if (n >= N) return;
    int k = t & 15;
    int lo = (n == 0) ? 0 : S[n - 1];
    int hi = S[n];
    float sum = g2[t];
    for (int e = lo; e < hi; ++e) {
        int s = eidx[e];
        sum += g2[s * H_DIM + k];
    }
    s2[t] = sum;
}

// ---------------- final: v = dinv*s2; logits = v@W2 + b2; log_softmax; coalesced writes ----------------

__global__ void __launch_bounds__(256) final_kernel(const float* __restrict__ s2,
                                                    const float* __restrict__ dinv,
                                                    const float* __restrict__ W2,
                                                    const float* __restrict__ b2,
                                                    float* __restrict__ out, int N) {
    __shared__ float w2s[H_DIM * C_DIM];
    __shared__ float b2s[C_DIM];
    __shared__ float stage[256 * 41];  // stride 41 to break bank conflicts
    for (int i = threadIdx.x; i < H_DIM * C_DIM; i += 256) w2s[i] = W2[i];
    if (threadIdx.x < C_DIM) b2s[threadIdx.x] = b2[threadIdx.x];
    __syncthreads();
    int n = blockIdx.x * 256 + threadIdx.x;
    int cn = n < N ? n : 0;
    float di = dinv[cn];
    float v[H_DIM];
    const float4* sv = (const float4*)(s2 + (size_t)cn * H_DIM);
#pragma unroll
    for (int p = 0; p < 4; p++) {
        float4 t = sv[p];
        v[4 * p] = di * t.x; v[4 * p + 1] = di * t.y;
        v[4 * p + 2] = di * t.z; v[4 * p + 3] = di * t.w;
    }
    float lg[C_DIM];
    float m = -1e30f;
    for (int c = 0; c < C_DIM; c++) {
        float a = b2s[c];
#pragma unroll
        for (int k = 0; k < H_DIM; k++) a += v[k] * w2s[k * C_DIM + c];
        lg[c] = a;
        m = fmaxf(m, a);
    }
    float ssum = 0.0f;
    for (int c = 0; c < C_DIM; c++) ssum += __expf(lg[c] - m);
    float lse = m + __logf(ssum);

    size_t base = (size_t)blockIdx.x * 256 * C_DIM;
    size_t lim = (size_t)N * C_DIM;
    // log_softmax
    for (int c = 0; c < C_DIM; c++) stage[threadIdx.x * 41 + c] = lg[c] - lse;
    __syncthreads();
    for (int i = threadIdx.x; i < 256 * C_DIM; i += 256) {
        int nn = i / C_DIM, c = i - nn * C_DIM;
        size_t g = base + i;
        if (g < lim) out[g] = stage[nn * 41 + c];
    }
    __syncthreads();
    // logits
    for (int c = 0; c < C_DIM; c++) stage[threadIdx.x * 41 + c] = lg[c];
    __syncthreads();
    for (int i = threadIdx.x; i < 256 * C_DIM; i += 256) {
        int nn = i / C_DIM, c = i - nn * C_DIM;
        size_t g = base + i;
        if (g < lim) out[lim + g] = stage[nn * 41 + c];
    }
}

// ---------------- launch ----------------

extern "C" void kernel_launch(void* const* d_in, const int* in_sizes, int n_in,
                              void* d_out, int out_size, void* d_ws, size_t ws_size,
                              hipStream_t stream) {
    const float* x  = (const float*)d_in[0];
    const int* ei   = (const int*)d_in[1];
    const float* W1 = (const float*)d_in[2];
    const float* b1 = (const float*)d_in[3];
    const float* W2 = (const float*)d_in[4];
    const float* b2 = (const float*)d_in[5];
    float* out = (float*)d_out;

    const int N = N_NODES;
    const int E = in_sizes[1] / 2;
    const int* src = ei;
    const int* dst = ei + E;

    // ws layout: S[N] int | BS[512] int | dinv[N] f | g1/s2[16N] f | g2[16N] f | eidx[E] int  (~26.4 MB)
    int* S      = (int*)d_ws;
    int* BS     = S + N;
    float* dinv = (float*)(BS + 512);
    float* g1   = dinv + N;        // reused as s2 after agg1 (g1 dead then)
    float* g2   = g1 + 16 * N;
    int* eidx   = (int*)(g2 + 16 * N);
    float* s2   = g1;

    const int NB = (N + 255) / 256;  // 391

    hipMemsetAsync(S, 0, (size_t)N * sizeof(int), stream);
    hist_kernel<<<(E + 255) / 256, 256, 0, stream>>>(dst, S, E);
    dinv_kernel<<<NB, 256, 0, stream>>>(S, dinv, N);
    scan1_kernel<<<NB, 256, 0, stream>>>(S, BS, N);
    scan2_kernel<<<1, 512, 0, stream>>>(BS, NB);
    scan3_kernel<<<NB, 256, 0, stream>>>(S, BS, N);
    reorder_kernel<<<(E + 255) / 256, 256, 0, stream>>>(src, dst, S, eidx, E);

    gemm1_kernel<<<(N + 1023) / 1024, 256, 0, stream>>>(x, W1, dinv, g1, N);
    agg1_kernel<<<(N * 16 + 255) / 256, 256, 0, stream>>>(S, eidx, g1, dinv, b1, g2, N);
    agg2_kernel<<<(N * 16 + 255) / 256, 256, 0, stream>>>(S, eidx, g2, s2, N);
    final_kernel<<<NB, 256, 0, stream>>>(s2, dinv, W2, b2, out, N);
}